// Round 2
// baseline (586.442 us; speedup 1.0000x reference)
//
#include <hip/hip_runtime.h>
#include <stdint.h>

// Problem constants
#define B_    16
#define S_    1024
#define D_    512
#define H_    8
#define DPH_  64
#define MTOT  (B_*S_)   // 16384 rows per tensor

typedef __attribute__((ext_vector_type(8))) short  short8;   // 8 x bf16
typedef __attribute__((ext_vector_type(4))) float  float4v;  // MFMA accumulator
typedef __attribute__((ext_vector_type(4))) ushort u16x4;

__device__ inline float bf2f(ushort u) {
    union { uint32_t u; float f; } c; c.u = ((uint32_t)u) << 16; return c.f;
}
__device__ inline ushort f2bf(float f) {  // round-to-nearest-even
    union { float f; uint32_t u; } c; c.f = f;
    uint32_t x = c.u;
    return (ushort)((x + 0x7fffu + ((x >> 16) & 1u)) >> 16);
}
// attn_scale = sqrt(512): fp32 bits 0x41B504F3 -> ushort[0] = 0x04F3 (fp32 layout)
// bf16 layout -> ushort[0] = 0x41B5. Unambiguous runtime dtype probe.
__device__ inline bool mode_f32(const void* as) {
    return ((const ushort*)as)[0] == (ushort)0x04F3u;
}

// ---------------------------------------------------------------------------
// Kernel 1: Y = X @ W^T + bias (fp32 out). 128x128 tile, BK=32, plain LDS
// staging. bf16 mode: 1 MFMA pass (exact products). fp32 mode: hi/lo bf16
// split, 3 passes (hi*hi + hi*lo + lo*hi) ~ fp32 accuracy.
// ---------------------------------------------------------------------------
__global__ __launch_bounds__(256) void gemm_proj(
    const void* __restrict__ Xq, const void* __restrict__ Xk, const void* __restrict__ Xv,
    const void* __restrict__ Wq, const void* __restrict__ Wk, const void* __restrict__ Wv,
    const void* __restrict__ bq, const void* __restrict__ bk, const void* __restrict__ bv,
    const void* __restrict__ as_flag,
    float* __restrict__ Yq, float* __restrict__ Yk, float* __restrict__ Yv)
{
    const int z = blockIdx.z;
    const void* X    = z == 0 ? Xq : (z == 1 ? Xk : Xv);
    const void* W    = z == 0 ? Wq : (z == 1 ? Wk : Wv);
    const void* bias = z == 0 ? bq : (z == 1 ? bk : bv);
    float*      Y    = z == 0 ? Yq : (z == 1 ? Yk : Yv);
    const bool  f32  = mode_f32(as_flag);

    const int m0   = blockIdx.x * 128;
    const int n0   = blockIdx.y * 128;
    const int tid  = threadIdx.x;
    const int lane = tid & 63;
    const int w    = tid >> 6;
    const int wm   = w >> 1, wn = w & 1;

    __shared__ ushort sAh[128 * 32];
    __shared__ ushort sBh[128 * 32];
    __shared__ ushort sAl[128 * 32];   // used only in fp32 mode
    __shared__ ushort sBl[128 * 32];

    float4v acc[4][4];
    #pragma unroll
    for (int i = 0; i < 4; ++i)
        #pragma unroll
        for (int j = 0; j < 4; ++j)
            acc[i][j] = (float4v){0.f, 0.f, 0.f, 0.f};

    for (int kt = 0; kt < D_; kt += 32) {
        __syncthreads();  // previous iteration's LDS reads complete
        if (!f32) {
            const ushort* Xu = (const ushort*)X;
            const ushort* Wu = (const ushort*)W;
            #pragma unroll
            for (int it = 0; it < 2; ++it) {
                const int chunk = tid + it * 256;        // 0..511 ushort8 chunks
                const int row = chunk >> 2, c8 = (chunk & 3) * 8;
                *(short8*)&sAh[row * 32 + c8] =
                    *(const short8*)&Xu[(size_t)(m0 + row) * D_ + kt + c8];
                *(short8*)&sBh[row * 32 + c8] =
                    *(const short8*)&Wu[(size_t)(n0 + row) * D_ + kt + c8];
            }
        } else {
            const float* Xf = (const float*)X;
            const float* Wf = (const float*)W;
            #pragma unroll
            for (int it = 0; it < 4; ++it) {
                const int chunk = tid + it * 256;        // 0..1023 float4 chunks
                const int row = chunk >> 3, c4 = (chunk & 7) * 4;
                const float4 fa = *(const float4*)&Xf[(size_t)(m0 + row) * D_ + kt + c4];
                const float4 fb = *(const float4*)&Wf[(size_t)(n0 + row) * D_ + kt + c4];
                u16x4 ah, al, bh, bl;
                #pragma unroll
                for (int q = 0; q < 4; ++q) {
                    const float fav = (&fa.x)[q], fbv = (&fb.x)[q];
                    const ushort ha = f2bf(fav), hb = f2bf(fbv);
                    ah[q] = ha; al[q] = f2bf(fav - bf2f(ha));
                    bh[q] = hb; bl[q] = f2bf(fbv - bf2f(hb));
                }
                *(u16x4*)&sAh[row * 32 + c4] = ah;
                *(u16x4*)&sAl[row * 32 + c4] = al;
                *(u16x4*)&sBh[row * 32 + c4] = bh;
                *(u16x4*)&sBl[row * 32 + c4] = bl;
            }
        }
        __syncthreads();

        const int fr = lane & 15;          // A: m index, B: n index
        const int fk = (lane >> 4) * 8;    // k offset (8 bf16)
        short8 a_h[4], b_h[4];
        #pragma unroll
        for (int i = 0; i < 4; ++i)
            a_h[i] = *(const short8*)&sAh[(wm * 64 + i * 16 + fr) * 32 + fk];
        #pragma unroll
        for (int j = 0; j < 4; ++j)
            b_h[j] = *(const short8*)&sBh[(wn * 64 + j * 16 + fr) * 32 + fk];
        #pragma unroll
        for (int i = 0; i < 4; ++i)
            #pragma unroll
            for (int j = 0; j < 4; ++j)
                acc[i][j] = __builtin_amdgcn_mfma_f32_16x16x32_bf16(a_h[i], b_h[j], acc[i][j], 0, 0, 0);
        if (f32) {
            short8 a_l[4], b_l[4];
            #pragma unroll
            for (int i = 0; i < 4; ++i)
                a_l[i] = *(const short8*)&sAl[(wm * 64 + i * 16 + fr) * 32 + fk];
            #pragma unroll
            for (int j = 0; j < 4; ++j)
                b_l[j] = *(const short8*)&sBl[(wn * 64 + j * 16 + fr) * 32 + fk];
            #pragma unroll
            for (int i = 0; i < 4; ++i)
                #pragma unroll
                for (int j = 0; j < 4; ++j) {
                    acc[i][j] = __builtin_amdgcn_mfma_f32_16x16x32_bf16(a_h[i], b_l[j], acc[i][j], 0, 0, 0);
                    acc[i][j] = __builtin_amdgcn_mfma_f32_16x16x32_bf16(a_l[i], b_h[j], acc[i][j], 0, 0, 0);
                }
        }
    }

    // epilogue: C/D layout col = lane&15, row = (lane>>4)*4 + reg  [m89/m91]
    const int fr = lane & 15;
    const int er = lane >> 4;
    #pragma unroll
    for (int j = 0; j < 4; ++j) {
        const int n = n0 + wn * 64 + j * 16 + fr;
        const float bvf = f32 ? ((const float*)bias)[n] : bf2f(((const ushort*)bias)[n]);
        #pragma unroll
        for (int i = 0; i < 4; ++i) {
            const int mb = m0 + wm * 64 + i * 16 + er * 4;
            #pragma unroll
            for (int r = 0; r < 4; ++r)
                Y[(size_t)(mb + r) * D_ + n] = acc[i][j][r] + bvf;
        }
    }
}

// ---------------------------------------------------------------------------
// Kernel 2: Lorentz transform, in place on fp32 Y. One block per row.
// ---------------------------------------------------------------------------
__global__ __launch_bounds__(256) void lorentz_k(
    float* __restrict__ Yq, float* __restrict__ Yk, float* __restrict__ Yv,
    const void* __restrict__ lq, const void* __restrict__ lk, const void* __restrict__ lv,
    const void* __restrict__ as_flag)
{
    const int z = blockIdx.y;
    float* Y = z == 0 ? Yq : (z == 1 ? Yk : Yv);
    const void* lsp = z == 0 ? lq : (z == 1 ? lk : lv);
    const bool f32 = mode_f32(as_flag);
    float* yr = Y + (size_t)blockIdx.x * D_;
    const int t = threadIdx.x;

    float2 v = *(const float2*)&yr[2 * t];
    float ss = v.y * v.y + (t ? v.x * v.x : 0.f);  // exclude element 0 (time slot)
    #pragma unroll
    for (int off = 32; off; off >>= 1) ss += __shfl_xor(ss, off, 64);

    __shared__ float red[4];
    __shared__ float bcast[2];
    if ((t & 63) == 0) red[t >> 6] = ss;
    __syncthreads();
    if (t == 0) {
        const float sq = fmaxf(red[0] + red[1] + red[2] + red[3], 1e-8f);
        const float y0 = v.x;
        const float ls = f32 ? ((const float*)lsp)[0] : bf2f(((const ushort*)lsp)[0]);
        const float time = (1.f / (1.f + expf(-y0))) * expf(ls) + 1.0f + 1e-4f;
        bcast[0] = time;
        bcast[1] = sqrtf((time * time - 1.0f) / sq);
    }
    __syncthreads();
    const float timev = bcast[0], sc = bcast[1];
    float2 o;
    o.x = (t == 0) ? timev : v.x * sc;
    o.y = v.y * sc;
    *(float2*)&yr[2 * t] = o;
}

// ---------------------------------------------------------------------------
// Kernel 3: per-(b,h) KV = k^T v (64x64) and Vsum over all S, fp64 accumulate.
// One block per bh; thread (te,td) owns a 4x4 block of KV.
// ---------------------------------------------------------------------------
__global__ __launch_bounds__(256) void kv_all(
    const float* __restrict__ K, const float* __restrict__ V,
    double* __restrict__ KV, double* __restrict__ Vs)
{
    const int bh = blockIdx.x;   // b*8 + h
    const int b = bh >> 3, h = bh & 7;
    const int t = threadIdx.x;
    const int td = t & 15, te = t >> 4;

    __shared__ float sK[16][64];
    __shared__ float sV[16][64];

    double acc[4][4] = {};
    double vs[4] = {0, 0, 0, 0};

    const int r  = t >> 4;          // staging row
    const int c4 = (t & 15) * 4;    // staging col (float4)
    const size_t rowbase = (size_t)b * S_ * D_ + (size_t)h * DPH_;

    for (int sc = 0; sc < S_; sc += 16) {
        __syncthreads();
        *(float4*)&sK[r][c4] = *(const float4*)&K[rowbase + (size_t)(sc + r) * D_ + c4];
        *(float4*)&sV[r][c4] = *(const float4*)&V[rowbase + (size_t)(sc + r) * D_ + c4];
        __syncthreads();
        #pragma unroll
        for (int rr = 0; rr < 16; ++rr) {
            const float4 k4 = *(const float4*)&sK[rr][te * 4];
            const float4 v4 = *(const float4*)&sV[rr][td * 4];
            #pragma unroll
            for (int i = 0; i < 4; ++i)
                #pragma unroll
                for (int j = 0; j < 4; ++j)
                    acc[i][j] += (double)((&k4.x)[i]) * (double)((&v4.x)[j]);
            #pragma unroll
            for (int j = 0; j < 4; ++j) vs[j] += (double)((&v4.x)[j]);
        }
    }

    double* kvout = KV + (size_t)bh * 4096;
    #pragma unroll
    for (int i = 0; i < 4; ++i)
        #pragma unroll
        for (int j = 0; j < 4; ++j)
            kvout[(te * 4 + i) * 64 + td * 4 + j] = acc[i][j];
    if (te == 0) {
        double* vout = Vs + (size_t)bh * 64;
        #pragma unroll
        for (int j = 0; j < 4; ++j) vout[td * 4 + j] = vs[j];
    }
}

// ---------------------------------------------------------------------------
// Kernel 4: ave = c0*Vsum + c1*(q*sgn)@KV ; ctx = ave/sqrt(clip(|sum sgn*ave^2|,1e-8))
// One block per (b,h, 64-row S-tile). Dual-dtype output.
// ---------------------------------------------------------------------------
__global__ __launch_bounds__(256) void ave_norm(
    const float* __restrict__ Q, const double* __restrict__ KV, const double* __restrict__ Vs,
    const void* __restrict__ as_ptr, const void* __restrict__ ab_ptr,
    void* __restrict__ outp)
{
    const int bid = blockIdx.x;       // 0..2047
    const int bh  = bid >> 4;
    const int st  = bid & 15;
    const int b = bh >> 3, h = bh & 7;
    const int s0 = st * 64;
    const int t = threadIdx.x;
    const int lane = t & 63;
    const int w = t >> 6;
    const bool f32 = mode_f32(as_ptr);

    __shared__ double sKV[64 * 64];  // 32 KB
    __shared__ double sVs[64];
    __shared__ float  sQ[64 * 64];   // 16 KB, sign pre-applied to e==0

    #pragma unroll 4
    for (int i = 0; i < 16; ++i)
        sKV[t + i * 256] = KV[(size_t)bh * 4096 + t + i * 256];
    if (t < 64) sVs[t] = Vs[(size_t)bh * 64 + t];
    #pragma unroll
    for (int i = 0; i < 16; ++i) {
        const int idx = t + i * 256;
        const int rr = idx >> 6, cc = idx & 63;
        const float qv = Q[((size_t)b * S_ + s0 + rr) * D_ + h * DPH_ + cc];
        sQ[idx] = (cc == 0) ? -qv : qv;
    }
    __syncthreads();

    const double asv = f32 ? (double)((const float*)as_ptr)[0]
                           : (double)bf2f(((const ushort*)as_ptr)[0]);
    const double abv = f32 ? (double)((const float*)ab_ptr)[0]
                           : (double)bf2f(((const ushort*)ab_ptr)[0]);
    const double c1 = 2.0 / asv;
    const double c0 = c1 + abv;

    for (int rc = 0; rc < 4; ++rc) {        // 4 chunks of 4 rows per wave
        const int rb = w * 16 + rc * 4;
        double dot[4] = {0, 0, 0, 0};
        for (int e4 = 0; e4 < 64; e4 += 4) {
            float4 q4[4];
            #pragma unroll
            for (int r = 0; r < 4; ++r)
                q4[r] = *(const float4*)&sQ[(rb + r) * 64 + e4];
            #pragma unroll
            for (int i = 0; i < 4; ++i) {
                const double kv = sKV[(e4 + i) * 64 + lane];
                #pragma unroll
                for (int r = 0; r < 4; ++r)
                    dot[r] += (double)((&q4[r].x)[i]) * kv;
            }
        }
        #pragma unroll
        for (int r = 0; r < 4; ++r) {
            const double a = c1 * dot[r] + c0 * sVs[lane];
            double tt = (lane == 0) ? -(a * a) : (a * a);
            #pragma unroll
            for (int off = 32; off; off >>= 1) tt += __shfl_xor(tt, off, 64);
            const double denom = sqrt(fmax(fabs(tt), 1e-8));
            const float cv = (float)(a / denom);
            const size_t oidx = ((size_t)b * S_ + s0 + rb + r) * D_ + h * DPH_ + lane;
            if (f32) ((float*)outp)[oidx] = cv;
            else     ((ushort*)outp)[oidx] = f2bf(cv);
        }
    }
}

// ---------------------------------------------------------------------------
// Workspace layout (bytes):
//   Yq 0           (33,554,432)  fp32 16384x512 (lorentz-transformed in place)
//   Yk 33,554,432  (33,554,432)
//   Yv 67,108,864  (33,554,432)
//   KV 100,663,296 ( 4,194,304)  fp64 128 x 64x64
//   Vs 104,857,600 (    65,536)  total 104,923,136 B
// ---------------------------------------------------------------------------
extern "C" void kernel_launch(void* const* d_in, const int* in_sizes, int n_in,
                              void* d_out, int out_size, void* d_ws, size_t ws_size,
                              hipStream_t stream)
{
    const void* key    = d_in[0];
    const void* value  = d_in[1];
    const void* query  = d_in[2];
    const void* Wq     = d_in[3];
    const void* bq     = d_in[4];
    const void* lsq    = d_in[5];
    const void* Wk     = d_in[6];
    const void* bk     = d_in[7];
    const void* lsk    = d_in[8];
    const void* Wv     = d_in[9];
    const void* bv     = d_in[10];
    const void* lsv    = d_in[11];
    const void* ascale = d_in[12];
    const void* abias  = d_in[13];

    char* ws = (char*)d_ws;
    float*  Yq = (float*)(ws + 0);
    float*  Yk = (float*)(ws + 33554432);
    float*  Yv = (float*)(ws + 67108864);
    double* KV = (double*)(ws + 100663296);
    double* Vs = (double*)(ws + 104857600);

    gemm_proj<<<dim3(MTOT / 128, D_ / 128, 3), 256, 0, stream>>>(
        query, key, value, Wq, Wk, Wv, bq, bk, bv, ascale, Yq, Yk, Yv);
    lorentz_k<<<dim3(MTOT, 3), 256, 0, stream>>>(Yq, Yk, Yv, lsq, lsk, lsv, ascale);
    kv_all<<<B_ * H_, 256, 0, stream>>>(Yk, Yv, KV, Vs);
    ave_norm<<<B_ * H_ * (S_ / 64), 256, 0, stream>>>(
        Yq, KV, Vs, ascale, abias, d_out);
}

// Round 3
// 453.944 us; speedup vs baseline: 1.2919x; 1.2919x over previous
//
#include <hip/hip_runtime.h>
#include <stdint.h>

// Problem constants
#define B_    16
#define S_    1024
#define D_    512
#define H_    8
#define DPH_  64
#define MTOT  (B_*S_)   // 16384 rows per tensor

typedef __attribute__((ext_vector_type(8))) short  short8;   // 8 x bf16
typedef __attribute__((ext_vector_type(4))) float  float4v;  // MFMA accumulator
typedef __attribute__((ext_vector_type(4))) ushort u16x4;

__device__ inline float bf2f(ushort u) {
    union { uint32_t u; float f; } c; c.u = ((uint32_t)u) << 16; return c.f;
}
__device__ inline ushort f2bf(float f) {  // round-to-nearest-even
    union { float f; uint32_t u; } c; c.f = f;
    uint32_t x = c.u;
    return (ushort)((x + 0x7fffu + ((x >> 16) & 1u)) >> 16);
}
// attn_scale = sqrt(512): fp32 bits 0x41B504F3 -> ushort[0]=0x04F3 (fp32 layout);
// bf16 layout -> 0x41B5. Unambiguous runtime dtype probe.
__device__ inline bool mode_f32(const void* as) {
    return ((const ushort*)as)[0] == (ushort)0x04F3u;
}

// ---------------------------------------------------------------------------
// Kernel 1: Y = X @ W^T + bias (fp32 out, RAW pre-lorentz), fused per-row
// stats: RowSq[z][m] += sum_{n!=0} y^2 (atomic), RowY0[z][m] = y(n==0).
// bf16 path: double-buffered LDS, 1 barrier/iter. fp32 path: hi/lo 3-pass.
// ---------------------------------------------------------------------------
__global__ __launch_bounds__(256) void gemm_proj(
    const void* __restrict__ Xq, const void* __restrict__ Xk, const void* __restrict__ Xv,
    const void* __restrict__ Wq, const void* __restrict__ Wk, const void* __restrict__ Wv,
    const void* __restrict__ bq, const void* __restrict__ bk, const void* __restrict__ bv,
    const void* __restrict__ as_flag,
    float* __restrict__ Yq, float* __restrict__ Yk, float* __restrict__ Yv,
    float* __restrict__ RowY0, float* __restrict__ RowSq)
{
    const int z = blockIdx.z;
    const void* X    = z == 0 ? Xq : (z == 1 ? Xk : Xv);
    const void* W    = z == 0 ? Wq : (z == 1 ? Wk : Wv);
    const void* bias = z == 0 ? bq : (z == 1 ? bk : bv);
    float*      Y    = z == 0 ? Yq : (z == 1 ? Yk : Yv);
    const bool  f32  = mode_f32(as_flag);

    const int m0   = blockIdx.x * 128;
    const int n0   = blockIdx.y * 128;
    const int tid  = threadIdx.x;
    const int lane = tid & 63;
    const int w    = tid >> 6;
    const int wm   = w >> 1, wn = w & 1;

    __shared__ __align__(16) char smem[32768];
    ushort* s16 = (ushort*)smem;

    float4v acc[4][4];
    #pragma unroll
    for (int i = 0; i < 4; ++i)
        #pragma unroll
        for (int j = 0; j < 4; ++j)
            acc[i][j] = (float4v){0.f, 0.f, 0.f, 0.f};

    const int fr = lane & 15;          // A: m index, B: n index
    const int fk = (lane >> 4) * 8;    // k offset (8 bf16)
    int offA[4], offB[4];
    #pragma unroll
    for (int i = 0; i < 4; ++i) offA[i] = (wm * 64 + i * 16 + fr) * 32 + fk;
    #pragma unroll
    for (int j = 0; j < 4; ++j) offB[j] = (wn * 64 + j * 16 + fr) * 32 + fk;

    if (!f32) {
        // -------- bf16 fast path: dbuf layout (ushort units):
        //   buf b: A @ b*8192, B @ b*8192+4096  (8 KB each)
        const ushort* Xu = (const ushort*)X;
        const ushort* Wu = (const ushort*)W;
        const int ca = tid, cb = tid + 256;          // 512 short8 chunks per tile
        const int ra0 = ca >> 2, ka0 = (ca & 3) * 8;
        const int ra1 = cb >> 2, ka1 = (cb & 3) * 8;
        const ushort* pA0 = Xu + (size_t)(m0 + ra0) * D_ + ka0;
        const ushort* pA1 = Xu + (size_t)(m0 + ra1) * D_ + ka1;
        const ushort* pB0 = Wu + (size_t)(n0 + ra0) * D_ + ka0;
        const ushort* pB1 = Wu + (size_t)(n0 + ra1) * D_ + ka1;
        const int da0 = ra0 * 32 + ka0, da1 = ra1 * 32 + ka1;

        // stage tile 0 into buf 0
        {
            short8 va0 = *(const short8*)pA0;
            short8 va1 = *(const short8*)pA1;
            short8 vb0 = *(const short8*)pB0;
            short8 vb1 = *(const short8*)pB1;
            *(short8*)&s16[da0]        = va0;
            *(short8*)&s16[da1]        = va1;
            *(short8*)&s16[4096 + da0] = vb0;
            *(short8*)&s16[4096 + da1] = vb1;
        }
        __syncthreads();
        int cur = 0;
        for (int kt = 32; kt < D_; kt += 32) {
            // prefetch next tile into regs (overlaps MFMA below via vmcnt)
            short8 na0 = *(const short8*)(pA0 + kt);
            short8 na1 = *(const short8*)(pA1 + kt);
            short8 nb0 = *(const short8*)(pB0 + kt);
            short8 nb1 = *(const short8*)(pB1 + kt);
            // compute current tile
            const ushort* bb = &s16[cur * 8192];
            short8 ah[4], bh[4];
            #pragma unroll
            for (int i = 0; i < 4; ++i) ah[i] = *(const short8*)&bb[offA[i]];
            #pragma unroll
            for (int j = 0; j < 4; ++j) bh[j] = *(const short8*)&bb[4096 + offB[j]];
            #pragma unroll
            for (int i = 0; i < 4; ++i)
                #pragma unroll
                for (int j = 0; j < 4; ++j)
                    acc[i][j] = __builtin_amdgcn_mfma_f32_16x16x32_bf16(ah[i], bh[j], acc[i][j], 0, 0, 0);
            // write next tile
            const int nxt = cur ^ 1;
            *(short8*)&s16[nxt * 8192 + da0]        = na0;
            *(short8*)&s16[nxt * 8192 + da1]        = na1;
            *(short8*)&s16[nxt * 8192 + 4096 + da0] = nb0;
            *(short8*)&s16[nxt * 8192 + 4096 + da1] = nb1;
            __syncthreads();
            cur = nxt;
        }
        {   // last tile
            const ushort* bb = &s16[cur * 8192];
            short8 ah[4], bh[4];
            #pragma unroll
            for (int i = 0; i < 4; ++i) ah[i] = *(const short8*)&bb[offA[i]];
            #pragma unroll
            for (int j = 0; j < 4; ++j) bh[j] = *(const short8*)&bb[4096 + offB[j]];
            #pragma unroll
            for (int i = 0; i < 4; ++i)
                #pragma unroll
                for (int j = 0; j < 4; ++j)
                    acc[i][j] = __builtin_amdgcn_mfma_f32_16x16x32_bf16(ah[i], bh[j], acc[i][j], 0, 0, 0);
        }
    } else {
        // -------- fp32 fallback: single-buffer 3-pass hi/lo split.
        //   Ah @ 0, Al @ 4096, Bx @ 8192 (ushort units), B staged hi then lo.
        const float* Xf = (const float*)X;
        const float* Wf = (const float*)W;
        for (int kt = 0; kt < D_; kt += 32) {
            __syncthreads();
            u16x4 rbl[4];
            #pragma unroll
            for (int it = 0; it < 4; ++it) {
                const int c = tid + it * 256;          // 1024 float4 chunks
                const int row = c >> 3, c4 = (c & 7) * 4;
                const float4 fa = *(const float4*)&Xf[(size_t)(m0 + row) * D_ + kt + c4];
                const float4 fb = *(const float4*)&Wf[(size_t)(n0 + row) * D_ + kt + c4];
                u16x4 ah4, al4, bh4;
                #pragma unroll
                for (int q = 0; q < 4; ++q) {
                    const float fav = (&fa.x)[q], fbv = (&fb.x)[q];
                    const ushort ha = f2bf(fav), hb = f2bf(fbv);
                    ah4[q] = ha; al4[q] = f2bf(fav - bf2f(ha));
                    bh4[q] = hb; rbl[it][q] = f2bf(fbv - bf2f(hb));
                }
                *(u16x4*)&s16[row * 32 + c4]        = ah4;
                *(u16x4*)&s16[4096 + row * 32 + c4] = al4;
                *(u16x4*)&s16[8192 + row * 32 + c4] = bh4;
            }
            __syncthreads();
            short8 ah[4], al[4], bx[4];
            #pragma unroll
            for (int i = 0; i < 4; ++i) {
                ah[i] = *(const short8*)&s16[offA[i]];
                al[i] = *(const short8*)&s16[4096 + offA[i]];
            }
            #pragma unroll
            for (int j = 0; j < 4; ++j) bx[j] = *(const short8*)&s16[8192 + offB[j]];
            #pragma unroll
            for (int i = 0; i < 4; ++i)
                #pragma unroll
                for (int j = 0; j < 4; ++j) {
                    acc[i][j] = __builtin_amdgcn_mfma_f32_16x16x32_bf16(ah[i], bx[j], acc[i][j], 0, 0, 0);
                    acc[i][j] = __builtin_amdgcn_mfma_f32_16x16x32_bf16(al[i], bx[j], acc[i][j], 0, 0, 0);
                }
            __syncthreads();
            #pragma unroll
            for (int it = 0; it < 4; ++it) {
                const int c = tid + it * 256;
                const int row = c >> 3, c4 = (c & 7) * 4;
                *(u16x4*)&s16[8192 + row * 32 + c4] = rbl[it];
            }
            __syncthreads();
            #pragma unroll
            for (int j = 0; j < 4; ++j) bx[j] = *(const short8*)&s16[8192 + offB[j]];
            #pragma unroll
            for (int i = 0; i < 4; ++i)
                #pragma unroll
                for (int j = 0; j < 4; ++j)
                    acc[i][j] = __builtin_amdgcn_mfma_f32_16x16x32_bf16(ah[i], bx[j], acc[i][j], 0, 0, 0);
        }
    }

    // -------- epilogue: store Y + per-row sumsq (excl global col 0) + y0.
    // C/D layout: col = lane&15, row = (lane>>4)*4 + reg   [m89/m91]
    __syncthreads();                       // allow smem reuse
    float* sRS = (float*)smem;             // [2][128]
    const int er = lane >> 4;
    float bvf[4];
    #pragma unroll
    for (int j = 0; j < 4; ++j) {
        const int n = n0 + wn * 64 + j * 16 + fr;
        bvf[j] = f32 ? ((const float*)bias)[n] : bf2f(((const ushort*)bias)[n]);
    }
    #pragma unroll
    for (int i = 0; i < 4; ++i)
        #pragma unroll
        for (int r = 0; r < 4; ++r) {
            const int row = wm * 64 + i * 16 + er * 4 + r;   // local row
            const int m = m0 + row;
            float rsum = 0.f;
            #pragma unroll
            for (int j = 0; j < 4; ++j) {
                const int n = n0 + wn * 64 + j * 16 + fr;
                const float y = acc[i][j][r] + bvf[j];
                Y[(size_t)m * D_ + n] = y;
                if (n != 0) rsum += y * y;
            }
            rsum += __shfl_xor(rsum, 1, 64);
            rsum += __shfl_xor(rsum, 2, 64);
            rsum += __shfl_xor(rsum, 4, 64);
            rsum += __shfl_xor(rsum, 8, 64);
            if (fr == 0) sRS[wn * 128 + row] = rsum;
            if (blockIdx.y == 0 && wn == 0 && fr == 0)
                RowY0[z * MTOT + m] = acc[i][0][r] + bvf[0];
        }
    __syncthreads();
    if (tid < 128) {
        const float v = sRS[tid] + sRS[128 + tid];
        atomicAdd(&RowSq[z * MTOT + m0 + tid], v);
    }
}

// ---------------------------------------------------------------------------
// Kernel 2: rowfix — per (z,m): T = time, A = sqrt((t^2-1)/clip(sq,1e-8)),
// computed in place over RowY0/RowSq.
// ---------------------------------------------------------------------------
__global__ __launch_bounds__(256) void rowfix(
    float* __restrict__ T, float* __restrict__ A,
    const void* __restrict__ lq, const void* __restrict__ lk, const void* __restrict__ lv,
    const void* __restrict__ as_flag)
{
    const int idx = blockIdx.x * 256 + threadIdx.x;   // 0..49151
    const int z = idx >> 14;
    const bool f32 = mode_f32(as_flag);
    const void* lsp = z == 0 ? lq : (z == 1 ? lk : lv);
    const float ls = f32 ? ((const float*)lsp)[0] : bf2f(((const ushort*)lsp)[0]);
    const float y0 = T[idx];
    const float sq = fmaxf(A[idx], 1e-8f);
    const float t = (1.f / (1.f + expf(-y0))) * expf(ls) + 1.0f + 1e-4f;
    T[idx] = t;
    A[idx] = sqrtf((t * t - 1.0f) / sq);
}

// ---------------------------------------------------------------------------
// Kernel 3: per-(b,h,sp) partial KV = k^T v (64x64) and Vsum; lorentz applied
// on load; fp64 local accumulate; fp32 atomic commit. Grid (128, 4).
// ---------------------------------------------------------------------------
__global__ __launch_bounds__(256) void kv_k(
    const float* __restrict__ Yk, const float* __restrict__ Yv,
    const float* __restrict__ T, const float* __restrict__ A,
    float* __restrict__ KV, float* __restrict__ Vs)
{
    const int bh = blockIdx.x;   // b*8 + h
    const int sp = blockIdx.y;   // 0..3
    const int b = bh >> 3, h = bh & 7;
    const int t = threadIdx.x;
    const int td = t & 15, te = t >> 4;

    __shared__ float sK[16][64];
    __shared__ float sV[16][64];

    double acc[4][4] = {};
    double vs[4] = {0, 0, 0, 0};

    const int r  = t >> 4;
    const int c4 = (t & 15) * 4;
    const size_t mbase = (size_t)b * S_ + (size_t)sp * 256;

    for (int sc = 0; sc < 256; sc += 16) {
        const size_t m = mbase + sc + r;
        __syncthreads();
        float4 kr = *(const float4*)&Yk[m * D_ + h * DPH_ + c4];
        float4 vr = *(const float4*)&Yv[m * D_ + h * DPH_ + c4];
        const float ak = A[MTOT + m],     tk = T[MTOT + m];
        const float av = A[2 * MTOT + m], tv = T[2 * MTOT + m];
        kr.x *= ak; kr.y *= ak; kr.z *= ak; kr.w *= ak;
        vr.x *= av; vr.y *= av; vr.z *= av; vr.w *= av;
        if (h == 0 && c4 == 0) { kr.x = tk; vr.x = tv; }
        *(float4*)&sK[r][c4] = kr;
        *(float4*)&sV[r][c4] = vr;
        __syncthreads();
        #pragma unroll
        for (int rr = 0; rr < 16; ++rr) {
            const float4 k4 = *(const float4*)&sK[rr][te * 4];
            const float4 v4 = *(const float4*)&sV[rr][td * 4];
            #pragma unroll
            for (int i = 0; i < 4; ++i)
                #pragma unroll
                for (int j = 0; j < 4; ++j)
                    acc[i][j] += (double)((&k4.x)[i]) * (double)((&v4.x)[j]);
            #pragma unroll
            for (int j = 0; j < 4; ++j) vs[j] += (double)((&v4.x)[j]);
        }
    }

    #pragma unroll
    for (int i = 0; i < 4; ++i)
        #pragma unroll
        for (int j = 0; j < 4; ++j)
            atomicAdd(&KV[(size_t)bh * 4096 + (te * 4 + i) * 64 + td * 4 + j],
                      (float)acc[i][j]);
    if (te == 0) {
        #pragma unroll
        for (int j = 0; j < 4; ++j)
            atomicAdd(&Vs[(size_t)bh * 64 + td * 4 + j], (float)vs[j]);
    }
}

// ---------------------------------------------------------------------------
// Kernel 4: ave = c0*Vsum + c1*(q~)@KV ; ctx = ave/sqrt(clip(|sum sgn*ave^2|,1e-8))
// q built on the fly from raw Yq + (T,A). One block per (b,h, 64-row tile).
// ---------------------------------------------------------------------------
__global__ __launch_bounds__(256) void ave_norm(
    const float* __restrict__ Yq, const float* __restrict__ T, const float* __restrict__ A,
    const float* __restrict__ KV, const float* __restrict__ Vs,
    const void* __restrict__ as_ptr, const void* __restrict__ ab_ptr,
    void* __restrict__ outp)
{
    const int bid = blockIdx.x;       // 0..2047
    const int bh  = bid >> 4;
    const int st  = bid & 15;
    const int b = bh >> 3, h = bh & 7;
    const int s0 = st * 64;
    const int t = threadIdx.x;
    const int lane = t & 63;
    const int w = t >> 6;
    const bool f32 = mode_f32(as_ptr);

    __shared__ float sKV[4096];   // 16 KB
    __shared__ float sQ[4096];    // 16 KB, lorentz + sign pre-applied

    #pragma unroll
    for (int i = 0; i < 16; ++i)
        sKV[t + i * 256] = KV[(size_t)bh * 4096 + t + i * 256];
    #pragma unroll
    for (int i = 0; i < 16; ++i) {
        const int idx = t + i * 256;
        const int rr = idx >> 6, cc = idx & 63;
        const size_t m = (size_t)b * S_ + s0 + rr;
        const float qraw = Yq[m * D_ + h * DPH_ + cc];
        const float qv = (h == 0 && cc == 0) ? T[m] : qraw * A[m];
        sQ[idx] = (cc == 0) ? -qv : qv;
    }
    const double vsl = (double)Vs[(size_t)bh * 64 + lane];
    __syncthreads();

    const double asv = f32 ? (double)((const float*)as_ptr)[0]
                           : (double)bf2f(((const ushort*)as_ptr)[0]);
    const double abv = f32 ? (double)((const float*)ab_ptr)[0]
                           : (double)bf2f(((const ushort*)ab_ptr)[0]);
    const double c1 = 2.0 / asv;
    const double c0 = c1 + abv;

    for (int rc = 0; rc < 4; ++rc) {        // 4 chunks of 4 rows per wave
        const int rb = w * 16 + rc * 4;
        double dot[4] = {0, 0, 0, 0};
        for (int e4 = 0; e4 < 64; e4 += 4) {
            float4 q4[4];
            #pragma unroll
            for (int r = 0; r < 4; ++r)
                q4[r] = *(const float4*)&sQ[(rb + r) * 64 + e4];
            #pragma unroll
            for (int i = 0; i < 4; ++i) {
                const double kv = (double)sKV[(e4 + i) * 64 + lane];
                #pragma unroll
                for (int r = 0; r < 4; ++r)
                    dot[r] += (double)((&q4[r].x)[i]) * kv;
            }
        }
        #pragma unroll
        for (int r = 0; r < 4; ++r) {
            const double a = c1 * dot[r] + c0 * vsl;
            double tt = (lane == 0) ? -(a * a) : (a * a);
            #pragma unroll
            for (int off = 32; off; off >>= 1) tt += __shfl_xor(tt, off, 64);
            const double denom = sqrt(fmax(fabs(tt), 1e-8));
            const float cv = (float)(a / denom);
            const size_t oidx = ((size_t)b * S_ + s0 + rb + r) * D_ + h * DPH_ + lane;
            if (f32) ((float*)outp)[oidx] = cv;
            else     ((ushort*)outp)[oidx] = f2bf(cv);
        }
    }
}

// ---------------------------------------------------------------------------
// Workspace layout (bytes):
//   Yq    0           (33,554,432)  fp32 raw (pre-lorentz)
//   Yk    33,554,432  (33,554,432)
//   Yv    67,108,864  (33,554,432)
//   T     100,663,296 (   196,608)  RowY0 -> time   (3 x 16384 fp32)
//   Alpha 100,859,904 (   196,608)  RowSq -> alpha  (memset 0 pre-gemm)
//   KV    101,056,512 ( 2,097,152)  fp32 128 x 64x64 (memset 0)
//   Vs    103,153,664 (    32,768)  fp32 128 x 64    (memset 0)
//   end   103,186,432  (< 104,923,136 proven-good)
// ---------------------------------------------------------------------------
extern "C" void kernel_launch(void* const* d_in, const int* in_sizes, int n_in,
                              void* d_out, int out_size, void* d_ws, size_t ws_size,
                              hipStream_t stream)
{
    const void* key    = d_in[0];
    const void* value  = d_in[1];
    const void* query  = d_in[2];
    const void* Wq     = d_in[3];
    const void* bq     = d_in[4];
    const void* lsq    = d_in[5];
    const void* Wk     = d_in[6];
    const void* bk     = d_in[7];
    const void* lsk    = d_in[8];
    const void* Wv     = d_in[9];
    const void* bv     = d_in[10];
    const void* lsv    = d_in[11];
    const void* ascale = d_in[12];
    const void* abias  = d_in[13];

    char* ws = (char*)d_ws;
    float* Yq    = (float*)(ws + 0);
    float* Yk    = (float*)(ws + 33554432);
    float* Yv    = (float*)(ws + 67108864);
    float* T     = (float*)(ws + 100663296);
    float* Alpha = (float*)(ws + 100859904);
    float* KV    = (float*)(ws + 101056512);
    float* Vs    = (float*)(ws + 103153664);

    // zero the atomic targets (Alpha/RowSq, KV, Vs are contiguous)
    hipMemsetAsync(ws + 100859904, 0, 2326528, stream);

    gemm_proj<<<dim3(MTOT / 128, D_ / 128, 3), 256, 0, stream>>>(
        query, key, value, Wq, Wk, Wv, bq, bk, bv, ascale,
        Yq, Yk, Yv, T, Alpha);
    rowfix<<<(3 * MTOT) / 256, 256, 0, stream>>>(T, Alpha, lsq, lsk, lsv, ascale);
    kv_k<<<dim3(B_ * H_, 4), 256, 0, stream>>>(Yk, Yv, T, Alpha, KV, Vs);
    ave_norm<<<B_ * H_ * (S_ / 64), 256, 0, stream>>>(
        Yq, T, Alpha, KV, Vs, ascale, abias, d_out);
}

// Round 4
// 339.666 us; speedup vs baseline: 1.7265x; 1.3364x over previous
//
#include <hip/hip_runtime.h>
#include <stdint.h>

// Problem constants
#define B_    16
#define S_    1024
#define D_    512
#define H_    8
#define DPH_  64
#define MTOT  (B_*S_)   // 16384 rows per tensor

typedef __attribute__((ext_vector_type(8))) short  short8;   // 8 x bf16
typedef __attribute__((ext_vector_type(4))) float  float4v;  // MFMA accumulator
typedef __attribute__((ext_vector_type(4))) ushort u16x4;

__device__ inline float bf2f(ushort u) {
    union { uint32_t u; float f; } c; c.u = ((uint32_t)u) << 16; return c.f;
}
__device__ inline ushort f2bf(float f) {  // round-to-nearest-even
    union { float f; uint32_t u; } c; c.f = f;
    uint32_t x = c.u;
    return (ushort)((x + 0x7fffu + ((x >> 16) & 1u)) >> 16);
}
// attn_scale = sqrt(512): fp32 bits 0x41B504F3 -> ushort[0]=0x04F3 (fp32 layout);
// bf16 layout -> 0x41B5. Unambiguous runtime dtype probe.
__device__ inline bool mode_f32(const void* as) {
    return ((const ushort*)as)[0] == (ushort)0x04F3u;
}

// ---------------------------------------------------------------------------
// Kernel 1: Y = X @ W^T + bias (fp32 out, RAW pre-lorentz), fused per-row
// stats: RowSq[z][m] += sum_{n!=0} y^2 (atomic), RowY0[z][m] = y(n==0).
// bf16 path: double-buffered LDS, 1 barrier/iter. fp32 path: hi/lo 3-pass.
// ---------------------------------------------------------------------------
__global__ __launch_bounds__(256) void gemm_proj(
    const void* __restrict__ Xq, const void* __restrict__ Xk, const void* __restrict__ Xv,
    const void* __restrict__ Wq, const void* __restrict__ Wk, const void* __restrict__ Wv,
    const void* __restrict__ bq, const void* __restrict__ bk, const void* __restrict__ bv,
    const void* __restrict__ as_flag,
    float* __restrict__ Yq, float* __restrict__ Yk, float* __restrict__ Yv,
    float* __restrict__ RowY0, float* __restrict__ RowSq)
{
    const int z = blockIdx.z;
    const void* X    = z == 0 ? Xq : (z == 1 ? Xk : Xv);
    const void* W    = z == 0 ? Wq : (z == 1 ? Wk : Wv);
    const void* bias = z == 0 ? bq : (z == 1 ? bk : bv);
    float*      Y    = z == 0 ? Yq : (z == 1 ? Yk : Yv);
    const bool  f32  = mode_f32(as_flag);

    const int m0   = blockIdx.x * 128;
    const int n0   = blockIdx.y * 128;
    const int tid  = threadIdx.x;
    const int lane = tid & 63;
    const int w    = tid >> 6;
    const int wm   = w >> 1, wn = w & 1;

    __shared__ __align__(16) char smem[32768];
    ushort* s16 = (ushort*)smem;

    float4v acc[4][4];
    #pragma unroll
    for (int i = 0; i < 4; ++i)
        #pragma unroll
        for (int j = 0; j < 4; ++j)
            acc[i][j] = (float4v){0.f, 0.f, 0.f, 0.f};

    const int fr = lane & 15;          // A: m index, B: n index
    const int fk = (lane >> 4) * 8;    // k offset (8 bf16)
    int offA[4], offB[4];
    #pragma unroll
    for (int i = 0; i < 4; ++i) offA[i] = (wm * 64 + i * 16 + fr) * 32 + fk;
    #pragma unroll
    for (int j = 0; j < 4; ++j) offB[j] = (wn * 64 + j * 16 + fr) * 32 + fk;

    if (!f32) {
        // -------- bf16 fast path: dbuf layout (ushort units):
        //   buf b: A @ b*8192, B @ b*8192+4096  (8 KB each)
        const ushort* Xu = (const ushort*)X;
        const ushort* Wu = (const ushort*)W;
        const int ca = tid, cb = tid + 256;          // 512 short8 chunks per tile
        const int ra0 = ca >> 2, ka0 = (ca & 3) * 8;
        const int ra1 = cb >> 2, ka1 = (cb & 3) * 8;
        const ushort* pA0 = Xu + (size_t)(m0 + ra0) * D_ + ka0;
        const ushort* pA1 = Xu + (size_t)(m0 + ra1) * D_ + ka1;
        const ushort* pB0 = Wu + (size_t)(n0 + ra0) * D_ + ka0;
        const ushort* pB1 = Wu + (size_t)(n0 + ra1) * D_ + ka1;
        const int da0 = ra0 * 32 + ka0, da1 = ra1 * 32 + ka1;

        // stage tile 0 into buf 0
        {
            short8 va0 = *(const short8*)pA0;
            short8 va1 = *(const short8*)pA1;
            short8 vb0 = *(const short8*)pB0;
            short8 vb1 = *(const short8*)pB1;
            *(short8*)&s16[da0]        = va0;
            *(short8*)&s16[da1]        = va1;
            *(short8*)&s16[4096 + da0] = vb0;
            *(short8*)&s16[4096 + da1] = vb1;
        }
        __syncthreads();
        int cur = 0;
        for (int kt = 32; kt < D_; kt += 32) {
            // prefetch next tile into regs (overlaps MFMA below via vmcnt)
            short8 na0 = *(const short8*)(pA0 + kt);
            short8 na1 = *(const short8*)(pA1 + kt);
            short8 nb0 = *(const short8*)(pB0 + kt);
            short8 nb1 = *(const short8*)(pB1 + kt);
            // compute current tile
            const ushort* bb = &s16[cur * 8192];
            short8 ah[4], bh[4];
            #pragma unroll
            for (int i = 0; i < 4; ++i) ah[i] = *(const short8*)&bb[offA[i]];
            #pragma unroll
            for (int j = 0; j < 4; ++j) bh[j] = *(const short8*)&bb[4096 + offB[j]];
            #pragma unroll
            for (int i = 0; i < 4; ++i)
                #pragma unroll
                for (int j = 0; j < 4; ++j)
                    acc[i][j] = __builtin_amdgcn_mfma_f32_16x16x32_bf16(ah[i], bh[j], acc[i][j], 0, 0, 0);
            // write next tile
            const int nxt = cur ^ 1;
            *(short8*)&s16[nxt * 8192 + da0]        = na0;
            *(short8*)&s16[nxt * 8192 + da1]        = na1;
            *(short8*)&s16[nxt * 8192 + 4096 + da0] = nb0;
            *(short8*)&s16[nxt * 8192 + 4096 + da1] = nb1;
            __syncthreads();
            cur = nxt;
        }
        {   // last tile
            const ushort* bb = &s16[cur * 8192];
            short8 ah[4], bh[4];
            #pragma unroll
            for (int i = 0; i < 4; ++i) ah[i] = *(const short8*)&bb[offA[i]];
            #pragma unroll
            for (int j = 0; j < 4; ++j) bh[j] = *(const short8*)&bb[4096 + offB[j]];
            #pragma unroll
            for (int i = 0; i < 4; ++i)
                #pragma unroll
                for (int j = 0; j < 4; ++j)
                    acc[i][j] = __builtin_amdgcn_mfma_f32_16x16x32_bf16(ah[i], bh[j], acc[i][j], 0, 0, 0);
        }
    } else {
        // -------- fp32 fallback: single-buffer 3-pass hi/lo split.
        //   Ah @ 0, Al @ 4096, Bx @ 8192 (ushort units), B staged hi then lo.
        const float* Xf = (const float*)X;
        const float* Wf = (const float*)W;
        for (int kt = 0; kt < D_; kt += 32) {
            __syncthreads();
            u16x4 rbl[4];
            #pragma unroll
            for (int it = 0; it < 4; ++it) {
                const int c = tid + it * 256;          // 1024 float4 chunks
                const int row = c >> 3, c4 = (c & 7) * 4;
                const float4 fa = *(const float4*)&Xf[(size_t)(m0 + row) * D_ + kt + c4];
                const float4 fb = *(const float4*)&Wf[(size_t)(n0 + row) * D_ + kt + c4];
                u16x4 ah4, al4, bh4;
                #pragma unroll
                for (int q = 0; q < 4; ++q) {
                    const float fav = (&fa.x)[q], fbv = (&fb.x)[q];
                    const ushort ha = f2bf(fav), hb = f2bf(fbv);
                    ah4[q] = ha; al4[q] = f2bf(fav - bf2f(ha));
                    bh4[q] = hb; rbl[it][q] = f2bf(fbv - bf2f(hb));
                }
                *(u16x4*)&s16[row * 32 + c4]        = ah4;
                *(u16x4*)&s16[4096 + row * 32 + c4] = al4;
                *(u16x4*)&s16[8192 + row * 32 + c4] = bh4;
            }
            __syncthreads();
            short8 ah[4], al[4], bx[4];
            #pragma unroll
            for (int i = 0; i < 4; ++i) {
                ah[i] = *(const short8*)&s16[offA[i]];
                al[i] = *(const short8*)&s16[4096 + offA[i]];
            }
            #pragma unroll
            for (int j = 0; j < 4; ++j) bx[j] = *(const short8*)&s16[8192 + offB[j]];
            #pragma unroll
            for (int i = 0; i < 4; ++i)
                #pragma unroll
                for (int j = 0; j < 4; ++j) {
                    acc[i][j] = __builtin_amdgcn_mfma_f32_16x16x32_bf16(ah[i], bx[j], acc[i][j], 0, 0, 0);
                    acc[i][j] = __builtin_amdgcn_mfma_f32_16x16x32_bf16(al[i], bx[j], acc[i][j], 0, 0, 0);
                }
            __syncthreads();
            #pragma unroll
            for (int it = 0; it < 4; ++it) {
                const int c = tid + it * 256;
                const int row = c >> 3, c4 = (c & 7) * 4;
                *(u16x4*)&s16[8192 + row * 32 + c4] = rbl[it];
            }
            __syncthreads();
            #pragma unroll
            for (int j = 0; j < 4; ++j) bx[j] = *(const short8*)&s16[8192 + offB[j]];
            #pragma unroll
            for (int i = 0; i < 4; ++i)
                #pragma unroll
                for (int j = 0; j < 4; ++j)
                    acc[i][j] = __builtin_amdgcn_mfma_f32_16x16x32_bf16(ah[i], bx[j], acc[i][j], 0, 0, 0);
        }
    }

    // -------- epilogue: store Y + per-row sumsq (excl global col 0) + y0.
    // C/D layout: col = lane&15, row = (lane>>4)*4 + reg   [m89/m91]
    __syncthreads();                       // allow smem reuse
    float* sRS = (float*)smem;             // [2][128]
    const int er = lane >> 4;
    float bvf[4];
    #pragma unroll
    for (int j = 0; j < 4; ++j) {
        const int n = n0 + wn * 64 + j * 16 + fr;
        bvf[j] = f32 ? ((const float*)bias)[n] : bf2f(((const ushort*)bias)[n]);
    }
    #pragma unroll
    for (int i = 0; i < 4; ++i)
        #pragma unroll
        for (int r = 0; r < 4; ++r) {
            const int row = wm * 64 + i * 16 + er * 4 + r;   // local row
            const int m = m0 + row;
            float rsum = 0.f;
            #pragma unroll
            for (int j = 0; j < 4; ++j) {
                const int n = n0 + wn * 64 + j * 16 + fr;
                const float y = acc[i][j][r] + bvf[j];
                Y[(size_t)m * D_ + n] = y;
                if (n != 0) rsum += y * y;
            }
            rsum += __shfl_xor(rsum, 1, 64);
            rsum += __shfl_xor(rsum, 2, 64);
            rsum += __shfl_xor(rsum, 4, 64);
            rsum += __shfl_xor(rsum, 8, 64);
            if (fr == 0) sRS[wn * 128 + row] = rsum;
            if (blockIdx.y == 0 && wn == 0 && fr == 0)
                RowY0[z * MTOT + m] = acc[i][0][r] + bvf[0];
        }
    __syncthreads();
    if (tid < 128) {
        const float v = sRS[tid] + sRS[128 + tid];
        atomicAdd(&RowSq[z * MTOT + m0 + tid], v);
    }
}

// ---------------------------------------------------------------------------
// Kernel 2: rowfix — per (z,m): T = time, A = sqrt((t^2-1)/clip(sq,1e-8)).
// ---------------------------------------------------------------------------
__global__ __launch_bounds__(256) void rowfix(
    float* __restrict__ T, float* __restrict__ A,
    const void* __restrict__ lq, const void* __restrict__ lk, const void* __restrict__ lv,
    const void* __restrict__ as_flag)
{
    const int idx = blockIdx.x * 256 + threadIdx.x;   // 0..49151
    const int z = idx >> 14;
    const bool f32 = mode_f32(as_flag);
    const void* lsp = z == 0 ? lq : (z == 1 ? lk : lv);
    const float ls = f32 ? ((const float*)lsp)[0] : bf2f(((const ushort*)lsp)[0]);
    const float y0 = T[idx];
    const float sq = fmaxf(A[idx], 1e-8f);
    const float t = (1.f / (1.f + expf(-y0))) * expf(ls) + 1.0f + 1e-4f;
    T[idx] = t;
    A[idx] = sqrtf((t * t - 1.0f) / sq);
}

// ---------------------------------------------------------------------------
// Kernel 3: per-(b,h,sp) partial KV = k^T v (64x64) and Vsum; lorentz applied
// on load; fp32 local accumulate (8-way S-split keeps chains short);
// fp32 atomic commit. Grid (128, 8).
// ---------------------------------------------------------------------------
__global__ __launch_bounds__(256) void kv_k(
    const float* __restrict__ Yk, const float* __restrict__ Yv,
    const float* __restrict__ T, const float* __restrict__ A,
    float* __restrict__ KV, float* __restrict__ Vs)
{
    const int bh = blockIdx.x;   // b*8 + h
    const int sp = blockIdx.y;   // 0..7
    const int b = bh >> 3, h = bh & 7;
    const int t = threadIdx.x;
    const int td = t & 15, te = t >> 4;

    __shared__ float sK[16][64];
    __shared__ float sV[16][64];

    float acc[4][4] = {};
    float vs[4] = {0.f, 0.f, 0.f, 0.f};

    const int r  = t >> 4;
    const int c4 = (t & 15) * 4;
    const size_t mbase = (size_t)b * S_ + (size_t)sp * 128;

    for (int sc = 0; sc < 128; sc += 16) {
        const size_t m = mbase + sc + r;
        __syncthreads();
        float4 kr = *(const float4*)&Yk[m * D_ + h * DPH_ + c4];
        float4 vr = *(const float4*)&Yv[m * D_ + h * DPH_ + c4];
        const float ak = A[MTOT + m],     tk = T[MTOT + m];
        const float av = A[2 * MTOT + m], tv = T[2 * MTOT + m];
        kr.x *= ak; kr.y *= ak; kr.z *= ak; kr.w *= ak;
        vr.x *= av; vr.y *= av; vr.z *= av; vr.w *= av;
        if (h == 0 && c4 == 0) { kr.x = tk; vr.x = tv; }
        *(float4*)&sK[r][c4] = kr;
        *(float4*)&sV[r][c4] = vr;
        __syncthreads();
        #pragma unroll
        for (int rr = 0; rr < 16; ++rr) {
            const float4 k4 = *(const float4*)&sK[rr][te * 4];
            const float4 v4 = *(const float4*)&sV[rr][td * 4];
            #pragma unroll
            for (int i = 0; i < 4; ++i)
                #pragma unroll
                for (int j = 0; j < 4; ++j)
                    acc[i][j] += (&k4.x)[i] * (&v4.x)[j];
            #pragma unroll
            for (int j = 0; j < 4; ++j) vs[j] += (&v4.x)[j];
        }
    }

    #pragma unroll
    for (int i = 0; i < 4; ++i)
        #pragma unroll
        for (int j = 0; j < 4; ++j)
            atomicAdd(&KV[(size_t)bh * 4096 + (te * 4 + i) * 64 + td * 4 + j],
                      acc[i][j]);
    if (te == 0) {
        #pragma unroll
        for (int j = 0; j < 4; ++j)
            atomicAdd(&Vs[(size_t)bh * 64 + td * 4 + j], vs[j]);
    }
}

// ---------------------------------------------------------------------------
// Kernel 4: ave = c1*(q~)@KV + c0*Vsum via hi/lo bf16 MFMA (3-pass, ~fp32
// accuracy); ctx = ave/sqrt(clip(|sum sgn*ave^2|,1e-8)). One block per
// (b,h, 128-row tile); wave = 32 rows; inner-product reduction done with
// shfl_xor on the MFMA C-layout quad groups.
// ---------------------------------------------------------------------------
__global__ __launch_bounds__(256) void ave_norm(
    const float* __restrict__ Yq, const float* __restrict__ T, const float* __restrict__ A,
    const float* __restrict__ KV, const float* __restrict__ Vs,
    const void* __restrict__ as_ptr, const void* __restrict__ ab_ptr,
    void* __restrict__ outp)
{
    const int bh = blockIdx.x >> 3;       // 0..127
    const int st = blockIdx.x & 7;        // 0..7  (128-row tile)
    const int b = bh >> 3, h = bh & 7;
    const int s0 = st * 128;
    const int t = threadIdx.x;
    const int lane = t & 63;
    const int w = t >> 6;
    const bool f32 = mode_f32(as_ptr);

    __shared__ ushort sKVh[64 * 64];   // 8 KB   KV^T hi  ([n=d_out][k=e])
    __shared__ ushort sKVl[64 * 64];   // 8 KB   KV^T lo
    __shared__ ushort sQh[128 * 64];   // 16 KB  q~ hi    ([m=row][k=e])
    __shared__ ushort sQl[128 * 64];   // 16 KB  q~ lo
    __shared__ float  sVs[64];

    // stage KV transposed, hi/lo split (one-time; write conflicts negligible)
    #pragma unroll
    for (int i = 0; i < 16; ++i) {
        const int idx = t + i * 256;            // e*64 + d
        const int e = idx >> 6, d = idx & 63;
        const float v = KV[(size_t)bh * 4096 + idx];
        const ushort hi = f2bf(v);
        sKVh[d * 64 + e] = hi;
        sKVl[d * 64 + e] = f2bf(v - bf2f(hi));
    }
    if (t < 64) sVs[t] = Vs[(size_t)bh * 64 + t];
    // stage q~ (lorentz + per-head sign on col 0), hi/lo split
    #pragma unroll
    for (int i = 0; i < 8; ++i) {
        const int idx = t + i * 256;            // float4 chunk: row*16 + c4/4
        const int row = idx >> 4, c4 = (idx & 15) * 4;
        const size_t m = (size_t)b * S_ + s0 + row;
        const float4 q4 = *(const float4*)&Yq[m * D_ + h * DPH_ + c4];
        const float alpha = A[m], tim = T[m];
        #pragma unroll
        for (int q = 0; q < 4; ++q) {
            const int col = c4 + q;
            float val = (&q4.x)[q] * alpha;
            if (h == 0 && col == 0) val = tim;
            if (col == 0) val = -val;
            const ushort hi = f2bf(val);
            sQh[row * 64 + col] = hi;
            sQl[row * 64 + col] = f2bf(val - bf2f(hi));
        }
    }
    __syncthreads();

    const float asv = f32 ? ((const float*)as_ptr)[0] : bf2f(((const ushort*)as_ptr)[0]);
    const float abv = f32 ? ((const float*)ab_ptr)[0] : bf2f(((const ushort*)ab_ptr)[0]);
    const float c1f = 2.0f / asv;
    const float c0f = c1f + abv;

    const int fr = lane & 15, fq = lane >> 4;

    float4v acc[2][4];
    #pragma unroll
    for (int mi = 0; mi < 2; ++mi)
        #pragma unroll
        for (int j = 0; j < 4; ++j)
            acc[mi][j] = (float4v){0.f, 0.f, 0.f, 0.f};

    #pragma unroll
    for (int kk = 0; kk < 2; ++kk) {
        const int ko = kk * 32 + fq * 8;
        short8 ah[2], al[2], bh4[4], bl4[4];
        #pragma unroll
        for (int mi = 0; mi < 2; ++mi) {
            ah[mi] = *(const short8*)&sQh[(w * 32 + mi * 16 + fr) * 64 + ko];
            al[mi] = *(const short8*)&sQl[(w * 32 + mi * 16 + fr) * 64 + ko];
        }
        #pragma unroll
        for (int j = 0; j < 4; ++j) {
            bh4[j] = *(const short8*)&sKVh[(j * 16 + fr) * 64 + ko];
            bl4[j] = *(const short8*)&sKVl[(j * 16 + fr) * 64 + ko];
        }
        #pragma unroll
        for (int mi = 0; mi < 2; ++mi)
            #pragma unroll
            for (int j = 0; j < 4; ++j) {
                acc[mi][j] = __builtin_amdgcn_mfma_f32_16x16x32_bf16(ah[mi], bh4[j], acc[mi][j], 0, 0, 0);
                acc[mi][j] = __builtin_amdgcn_mfma_f32_16x16x32_bf16(ah[mi], bl4[j], acc[mi][j], 0, 0, 0);
                acc[mi][j] = __builtin_amdgcn_mfma_f32_16x16x32_bf16(al[mi], bh4[j], acc[mi][j], 0, 0, 0);
            }
    }

    // epilogue: C layout col = lane&15, row = fq*4 + reg
    #pragma unroll
    for (int mi = 0; mi < 2; ++mi) {
        float avev[4][4];   // [j][r]
        float part[4] = {0.f, 0.f, 0.f, 0.f};
        #pragma unroll
        for (int j = 0; j < 4; ++j) {
            const float vsn = sVs[j * 16 + fr];
            #pragma unroll
            for (int r = 0; r < 4; ++r) {
                const float a = c1f * acc[mi][j][r] + c0f * vsn;
                avev[j][r] = a;
                part[r] += (j == 0 && fr == 0) ? -(a * a) : (a * a);
            }
        }
        #pragma unroll
        for (int off = 1; off < 16; off <<= 1)
            #pragma unroll
            for (int r = 0; r < 4; ++r)
                part[r] += __shfl_xor(part[r], off, 64);
        float rd[4];
        #pragma unroll
        for (int r = 0; r < 4; ++r)
            rd[r] = 1.0f / sqrtf(fmaxf(fabsf(part[r]), 1e-8f));
        #pragma unroll
        for (int j = 0; j < 4; ++j)
            #pragma unroll
            for (int r = 0; r < 4; ++r) {
                const int srow = s0 + w * 32 + mi * 16 + fq * 4 + r;
                const size_t oidx = ((size_t)b * S_ + srow) * D_ + h * DPH_ + j * 16 + fr;
                const float cv = avev[j][r] * rd[r];
                if (f32) ((float*)outp)[oidx] = cv;
                else     ((ushort*)outp)[oidx] = f2bf(cv);
            }
    }
}

// ---------------------------------------------------------------------------
// Workspace layout (bytes):
//   Yq    0           (33,554,432)  fp32 raw (pre-lorentz)
//   Yk    33,554,432  (33,554,432)
//   Yv    67,108,864  (33,554,432)
//   T     100,663,296 (   196,608)  RowY0 -> time   (3 x 16384 fp32)
//   Alpha 100,859,904 (   196,608)  RowSq -> alpha  (memset 0 pre-gemm)
//   KV    101,056,512 ( 2,097,152)  fp32 128 x 64x64 (memset 0)
//   Vs    103,153,664 (    32,768)  fp32 128 x 64    (memset 0)
//   end   103,186,432  (< 104,923,136 proven-good)
// ---------------------------------------------------------------------------
extern "C" void kernel_launch(void* const* d_in, const int* in_sizes, int n_in,
                              void* d_out, int out_size, void* d_ws, size_t ws_size,
                              hipStream_t stream)
{
    const void* key    = d_in[0];
    const void* value  = d_in[1];
    const void* query  = d_in[2];
    const void* Wq     = d_in[3];
    const void* bq     = d_in[4];
    const void* lsq    = d_in[5];
    const void* Wk     = d_in[6];
    const void* bk     = d_in[7];
    const void* lsk    = d_in[8];
    const void* Wv     = d_in[9];
    const void* bv     = d_in[10];
    const void* lsv    = d_in[11];
    const void* ascale = d_in[12];
    const void* abias  = d_in[13];

    char* ws = (char*)d_ws;
    float* Yq    = (float*)(ws + 0);
    float* Yk    = (float*)(ws + 33554432);
    float* Yv    = (float*)(ws + 67108864);
    float* T     = (float*)(ws + 100663296);
    float* Alpha = (float*)(ws + 100859904);
    float* KV    = (float*)(ws + 101056512);
    float* Vs    = (float*)(ws + 103153664);

    // zero the atomic targets (Alpha/RowSq, KV, Vs are contiguous)
    hipMemsetAsync(ws + 100859904, 0, 2326528, stream);

    gemm_proj<<<dim3(MTOT / 128, D_ / 128, 3), 256, 0, stream>>>(
        query, key, value, Wq, Wk, Wv, bq, bk, bv, ascale,
        Yq, Yk, Yv, T, Alpha);
    rowfix<<<(3 * MTOT) / 256, 256, 0, stream>>>(T, Alpha, lsq, lsk, lsv, ascale);
    kv_k<<<dim3(B_ * H_, 8), 256, 0, stream>>>(Yk, Yv, T, Alpha, KV, Vs);
    ave_norm<<<B_ * H_ * (S_ / 128), 256, 0, stream>>>(
        Yq, T, Alpha, KV, Vs, ascale, abias, d_out);
}